// Round 3
// baseline (68.095 us; speedup 1.0000x reference)
//
#include <hip/hip_runtime.h>
#include <hip/hip_bf16.h>

#define KDIM  1024
#define NOUT  1024
#define NTOK  8192
#define NCB   16

typedef __attribute__((ext_vector_type(8))) short short8;
typedef __attribute__((ext_vector_type(4))) float f32x4;

__device__ static inline unsigned short f2bf(float f) {
    unsigned int u = __float_as_uint(f);
    return (unsigned short)((u + 0x7FFFu + ((u >> 16) & 1u)) >> 16);
}

__device__ static inline float bf2f(unsigned int h) {
    return __uint_as_float(h << 16);
}

__device__ static inline void async_copy16(const void* g, void* l) {
    __builtin_amdgcn_global_load_lds(
        (const __attribute__((address_space(1))) void*)g,
        (__attribute__((address_space(3))) void*)l, 16, 0, 0);
}

__device__ static inline short8 cvt8(float4 a, float4 b) {
    short8 o;
    o[0] = (short)f2bf(a.x); o[1] = (short)f2bf(a.y);
    o[2] = (short)f2bf(a.z); o[3] = (short)f2bf(a.w);
    o[4] = (short)f2bf(b.x); o[5] = (short)f2bf(b.y);
    o[6] = (short)f2bf(b.z); o[7] = (short)f2bf(b.w);
    return o;
}

// ---- weight fp32 [16][1024][64] -> bf16 Bt [n=1024][k=1024], n = h*64+o ----
__global__ __launch_bounds__(256) void conv_w_kernel(const float* __restrict__ W,
                                                     unsigned short* __restrict__ Bt) {
    int u = blockIdx.x * 256 + threadIdx.x;
    int n  = u & (NOUT - 1);
    int k0 = (u >> 10) << 3;
    int h = n >> 6, o = n & 63;
    const float* src = W + (size_t)h * KDIM * 64 + o;
    short8 v;
#pragma unroll
    for (int j = 0; j < 8; ++j)
        v[j] = (short)f2bf(src[(size_t)(k0 + j) * 64]);
    *(short8*)(Bt + (size_t)n * KDIM + k0) = v;
}

// ---- GEMM fused with x-convert: Y[m][n] = sum_k bf16(x[m][k])*Bt[n][k] ----
// 128x128 tile, BK=32, 256 threads (4 waves, 2x2 of 64x64), double-buffered,
// issue-early staging. XOR chunk-swizzle (c ^= (row>>1)&3) on A and B tiles.
__global__ __launch_bounds__(256) void gemm_fused_kernel(const float* __restrict__ x,
                                                         const unsigned short* __restrict__ Bt,
                                                         unsigned short* __restrict__ Y) {
    __shared__ unsigned short Bl[2][128 * 32];
    __shared__ unsigned short Al[2][128 * 32];

    const int tid = threadIdx.x;
    const int n0 = blockIdx.x * 128;
    const int m0 = blockIdx.y * 128;
    const int lane = tid & 63;
    const int w = tid >> 6;
    const int wr = (w >> 1) * 64;
    const int wc = (w & 1) * 64;
    const int r15 = lane & 15;
    const int kq = (lane >> 4) * 8;
    const int cl = kq >> 3;          // logical 16B chunk 0..3

    // A reg-stage geometry: 2 threads/row, 16 fp32 each
    const int arow = tid >> 1;
    const int ac0  = (tid & 1) * 2;  // logical chunks {ac0, ac0+1}
    const int aswz = (arow >> 1) & 3;
    const float* xsrc = x + (size_t)(m0 + arow) * KDIM + (tid & 1) * 16;

    f32x4 acc[4][4];
#pragma unroll
    for (int m = 0; m < 4; ++m)
#pragma unroll
        for (int n = 0; n < 4; ++n)
            acc[m][n] = (f32x4){0.f, 0.f, 0.f, 0.f};

    // ---- prologue: tile 0 ----
#pragma unroll
    for (int i = 0; i < 2; ++i) {
        int slot = i * 256 + tid;
        int row = slot >> 2, ch = slot & 3;
        int ks = ((ch ^ ((row >> 1) & 3)) << 3);
        async_copy16(Bt + (size_t)(n0 + row) * KDIM + ks, &Bl[0][slot * 8]);
    }
    {
        float4 p0 = *(const float4*)(xsrc);
        float4 p1 = *(const float4*)(xsrc + 4);
        float4 p2 = *(const float4*)(xsrc + 8);
        float4 p3 = *(const float4*)(xsrc + 12);
        *(short8*)&Al[0][arow * 32 + ((ac0 ^ aswz) << 3)]       = cvt8(p0, p1);
        *(short8*)&Al[0][arow * 32 + (((ac0 + 1) ^ aswz) << 3)] = cvt8(p2, p3);
    }
    __syncthreads();

    for (int t = 0; t < 32; ++t) {
        const int b = t & 1;
        float4 p0, p1, p2, p3;
        if (t < 31) {
            const int kt = (t + 1) * 32;
#pragma unroll
            for (int i = 0; i < 2; ++i) {
                int slot = i * 256 + tid;
                int row = slot >> 2, ch = slot & 3;
                int ks = ((ch ^ ((row >> 1) & 3)) << 3);
                async_copy16(Bt + (size_t)(n0 + row) * KDIM + kt + ks, &Bl[b ^ 1][slot * 8]);
            }
            p0 = *(const float4*)(xsrc + kt);
            p1 = *(const float4*)(xsrc + kt + 4);
            p2 = *(const float4*)(xsrc + kt + 8);
            p3 = *(const float4*)(xsrc + kt + 12);
        }

        short8 af[4], bfr[4];
#pragma unroll
        for (int m = 0; m < 4; ++m) {
            int ra = wr + m * 16 + r15;
            af[m] = *(const short8*)&Al[b][ra * 32 + ((cl ^ ((ra >> 1) & 3)) << 3)];
        }
#pragma unroll
        for (int n = 0; n < 4; ++n) {
            int rb = wc + n * 16 + r15;
            bfr[n] = *(const short8*)&Bl[b][rb * 32 + ((cl ^ ((rb >> 1) & 3)) << 3)];
        }
#pragma unroll
        for (int m = 0; m < 4; ++m)
#pragma unroll
            for (int n = 0; n < 4; ++n)
                acc[m][n] = __builtin_amdgcn_mfma_f32_16x16x32_bf16(af[m], bfr[n], acc[m][n], 0, 0, 0);

        if (t < 31) {
            *(short8*)&Al[b ^ 1][arow * 32 + ((ac0 ^ aswz) << 3)]       = cvt8(p0, p1);
            *(short8*)&Al[b ^ 1][arow * 32 + (((ac0 + 1) ^ aswz) << 3)] = cvt8(p2, p3);
        }
        __syncthreads();
    }

    // write back: D layout col=lane&15, row=(lane>>4)*4+r
    const int rrow = (lane >> 4) * 4;
#pragma unroll
    for (int m = 0; m < 4; ++m) {
#pragma unroll
        for (int n = 0; n < 4; ++n) {
            int col = n0 + wc + n * 16 + r15;
#pragma unroll
            for (int r = 0; r < 4; ++r) {
                int row = m0 + wr + m * 16 + rrow + r;
                Y[(size_t)row * NOUT + col] = f2bf(acc[m][n][r]);
            }
        }
    }
}

// ---- epilogue: outer product + mean*sqrt(h) + rms_norm; 1 block/token ----
__global__ __launch_bounds__(256) void epilogue_kernel(const unsigned short* __restrict__ Y,
                                                       float* __restrict__ out) {
    __shared__ float ylds[1024];
    __shared__ float red[4];

    const int t = blockIdx.x;
    const int tid = threadIdx.x;
    const unsigned short* yrow = Y + (size_t)t * NOUT;

    {
        uint2 raw = *(const uint2*)(yrow + tid * 4);
        ylds[tid * 4 + 0] = bf2f(raw.x & 0xffffu);
        ylds[tid * 4 + 1] = bf2f(raw.x >> 16);
        ylds[tid * 4 + 2] = bf2f(raw.y & 0xffffu);
        ylds[tid * 4 + 3] = bf2f(raw.y >> 16);
    }
    __syncthreads();

    const int j = tid >> 3;
    const int k0 = (tid & 7) * 4;

    float o0 = 0.f, o1 = 0.f, o2 = 0.f, o3 = 0.f;
#pragma unroll
    for (int h = 0; h < NCB; ++h) {
        float a = ylds[h * 64 + j];
        float4 bb = *(const float4*)&ylds[h * 64 + 32 + k0];
        o0 += a * bb.x; o1 += a * bb.y; o2 += a * bb.z; o3 += a * bb.w;
    }
    o0 *= 0.25f; o1 *= 0.25f; o2 *= 0.25f; o3 *= 0.25f;

    float ss = o0 * o0 + o1 * o1 + o2 * o2 + o3 * o3;
#pragma unroll
    for (int off = 32; off >= 1; off >>= 1)
        ss += __shfl_xor(ss, off, 64);

    const int lane = tid & 63, w = tid >> 6;
    if (lane == 0) red[w] = ss;
    __syncthreads();
    float tot = red[0] + red[1] + red[2] + red[3];
    float scale = rsqrtf(tot * (1.0f / 1024.0f) + 1e-12f);

    float4 o;
    o.x = o0 * scale; o.y = o1 * scale; o.z = o2 * scale; o.w = o3 * scale;
    *(float4*)(out + (size_t)t * 1024 + tid * 4) = o;
}

extern "C" void kernel_launch(void* const* d_in, const int* in_sizes, int n_in,
                              void* d_out, int out_size, void* d_ws, size_t ws_size,
                              hipStream_t stream) {
    const float* x   = (const float*)d_in[0];
    const float* wgt = (const float*)d_in[1];
    float* out = (float*)d_out;

    unsigned short* Bt = (unsigned short*)d_ws;                       //  2 MB
    unsigned short* Y  = (unsigned short*)((char*)d_ws + (2u << 20)); // 16 MB

    conv_w_kernel<<<NOUT * KDIM / 8 / 256, 256, 0, stream>>>(wgt, Bt);
    gemm_fused_kernel<<<dim3(NOUT / 128, NTOK / 128), 256, 0, stream>>>(x, Bt, Y);
    epilogue_kernel<<<NTOK, 256, 0, stream>>>(Y, out);
}

// Round 4
// 63.063 us; speedup vs baseline: 1.0798x; 1.0798x over previous
//
#include <hip/hip_runtime.h>
#include <hip/hip_bf16.h>

#define KDIM  1024
#define NOUT  1024
#define NTOK  8192
#define NCB   16

typedef __attribute__((ext_vector_type(8))) short short8;
typedef __attribute__((ext_vector_type(4))) float f32x4;

__device__ static inline unsigned short f2bf(float f) {
    unsigned int u = __float_as_uint(f);
    return (unsigned short)((u + 0x7FFFu + ((u >> 16) & 1u)) >> 16);
}

__device__ static inline float bf2f(unsigned int h) {
    return __uint_as_float(h << 16);
}

__device__ static inline void async_copy16(const void* g, void* l) {
    __builtin_amdgcn_global_load_lds(
        (const __attribute__((address_space(1))) void*)g,
        (__attribute__((address_space(3))) void*)l, 16, 0, 0);
}

__device__ static inline short8 cvt8(float4 a, float4 b) {
    short8 o;
    o[0] = (short)f2bf(a.x); o[1] = (short)f2bf(a.y);
    o[2] = (short)f2bf(a.z); o[3] = (short)f2bf(a.w);
    o[4] = (short)f2bf(b.x); o[5] = (short)f2bf(b.y);
    o[6] = (short)f2bf(b.z); o[7] = (short)f2bf(b.w);
    return o;
}

// ---- weight fp32 [16][1024][64] -> bf16 Bt [n=1024][k=1024], n = h*64+o ----
__global__ __launch_bounds__(256) void conv_w_kernel(const float* __restrict__ W,
                                                     unsigned short* __restrict__ Bt) {
    int u = blockIdx.x * 256 + threadIdx.x;
    int n  = u & (NOUT - 1);
    int k0 = (u >> 10) << 3;
    int h = n >> 6, o = n & 63;
    const float* src = W + (size_t)h * KDIM * 64 + o;
    short8 v;
#pragma unroll
    for (int j = 0; j < 8; ++j)
        v[j] = (short)f2bf(src[(size_t)(k0 + j) * 64]);
    *(short8*)(Bt + (size_t)n * KDIM + k0) = v;
}

// ---- GEMM fused with x-convert: Y[m][n] = sum_k bf16(x[m][k])*Bt[n][k] ----
// 128x128 tile, BK=32, 256 threads (4 waves, 2x2 of 64x64), double-buffered,
// issue-early staging, XOR chunk-swizzle on A and B tiles.
// XCD-aware block remap: xcd=id&7 owns m-panels [xcd*8, xcd*8+8) x all n,
// so the 8 n-blocks sharing an x m-panel sit on one XCD's L2.
__global__ __launch_bounds__(256) void gemm_fused_kernel(const float* __restrict__ x,
                                                         const unsigned short* __restrict__ Bt,
                                                         unsigned short* __restrict__ Y) {
    __shared__ unsigned short Bl[2][128 * 32];
    __shared__ unsigned short Al[2][128 * 32];

    const int id   = blockIdx.x;
    const int xcd  = id & 7;
    const int j    = id >> 3;
    const int m0   = (xcd * 8 + (j >> 3)) * 128;
    const int n0   = (j & 7) * 128;

    const int tid = threadIdx.x;
    const int lane = tid & 63;
    const int w = tid >> 6;
    const int wr = (w >> 1) * 64;
    const int wc = (w & 1) * 64;
    const int r15 = lane & 15;
    const int kq = (lane >> 4) * 8;
    const int cl = kq >> 3;          // logical 16B chunk 0..3

    // A reg-stage geometry: 2 threads/row, 16 fp32 each
    const int arow = tid >> 1;
    const int ac0  = (tid & 1) * 2;  // logical chunks {ac0, ac0+1}
    const int aswz = (arow >> 1) & 3;
    const float* xsrc = x + (size_t)(m0 + arow) * KDIM + (tid & 1) * 16;

    f32x4 acc[4][4];
#pragma unroll
    for (int m = 0; m < 4; ++m)
#pragma unroll
        for (int n = 0; n < 4; ++n)
            acc[m][n] = (f32x4){0.f, 0.f, 0.f, 0.f};

    // ---- prologue: tile 0 ----
#pragma unroll
    for (int i = 0; i < 2; ++i) {
        int slot = i * 256 + tid;
        int row = slot >> 2, ch = slot & 3;
        int ks = ((ch ^ ((row >> 1) & 3)) << 3);
        async_copy16(Bt + (size_t)(n0 + row) * KDIM + ks, &Bl[0][slot * 8]);
    }
    {
        float4 p0 = *(const float4*)(xsrc);
        float4 p1 = *(const float4*)(xsrc + 4);
        float4 p2 = *(const float4*)(xsrc + 8);
        float4 p3 = *(const float4*)(xsrc + 12);
        *(short8*)&Al[0][arow * 32 + ((ac0 ^ aswz) << 3)]       = cvt8(p0, p1);
        *(short8*)&Al[0][arow * 32 + (((ac0 + 1) ^ aswz) << 3)] = cvt8(p2, p3);
    }
    __syncthreads();

    for (int t = 0; t < 32; ++t) {
        const int b = t & 1;
        float4 p0, p1, p2, p3;
        if (t < 31) {
            const int kt = (t + 1) * 32;
#pragma unroll
            for (int i = 0; i < 2; ++i) {
                int slot = i * 256 + tid;
                int row = slot >> 2, ch = slot & 3;
                int ks = ((ch ^ ((row >> 1) & 3)) << 3);
                async_copy16(Bt + (size_t)(n0 + row) * KDIM + kt + ks, &Bl[b ^ 1][slot * 8]);
            }
            p0 = *(const float4*)(xsrc + kt);
            p1 = *(const float4*)(xsrc + kt + 4);
            p2 = *(const float4*)(xsrc + kt + 8);
            p3 = *(const float4*)(xsrc + kt + 12);
        }

        short8 af[4], bfr[4];
#pragma unroll
        for (int m = 0; m < 4; ++m) {
            int ra = wr + m * 16 + r15;
            af[m] = *(const short8*)&Al[b][ra * 32 + ((cl ^ ((ra >> 1) & 3)) << 3)];
        }
#pragma unroll
        for (int n = 0; n < 4; ++n) {
            int rb = wc + n * 16 + r15;
            bfr[n] = *(const short8*)&Bl[b][rb * 32 + ((cl ^ ((rb >> 1) & 3)) << 3)];
        }
#pragma unroll
        for (int m = 0; m < 4; ++m)
#pragma unroll
            for (int n = 0; n < 4; ++n)
                acc[m][n] = __builtin_amdgcn_mfma_f32_16x16x32_bf16(af[m], bfr[n], acc[m][n], 0, 0, 0);

        if (t < 31) {
            *(short8*)&Al[b ^ 1][arow * 32 + ((ac0 ^ aswz) << 3)]       = cvt8(p0, p1);
            *(short8*)&Al[b ^ 1][arow * 32 + (((ac0 + 1) ^ aswz) << 3)] = cvt8(p2, p3);
        }
        __syncthreads();
    }

    // write back: D layout col=lane&15, row=(lane>>4)*4+r
    const int rrow = (lane >> 4) * 4;
#pragma unroll
    for (int m = 0; m < 4; ++m) {
#pragma unroll
        for (int n = 0; n < 4; ++n) {
            int col = n0 + wc + n * 16 + r15;
#pragma unroll
            for (int r = 0; r < 4; ++r) {
                int row = m0 + wr + m * 16 + rrow + r;
                Y[(size_t)row * NOUT + col] = f2bf(acc[m][n][r]);
            }
        }
    }
}

// ---- epilogue: outer product + mean*sqrt(h) + rms_norm; 1 block/token ----
__global__ __launch_bounds__(256) void epilogue_kernel(const unsigned short* __restrict__ Y,
                                                       float* __restrict__ out) {
    __shared__ float ylds[1024];
    __shared__ float red[4];

    const int t = blockIdx.x;
    const int tid = threadIdx.x;
    const unsigned short* yrow = Y + (size_t)t * NOUT;

    {
        uint2 raw = *(const uint2*)(yrow + tid * 4);
        ylds[tid * 4 + 0] = bf2f(raw.x & 0xffffu);
        ylds[tid * 4 + 1] = bf2f(raw.x >> 16);
        ylds[tid * 4 + 2] = bf2f(raw.y & 0xffffu);
        ylds[tid * 4 + 3] = bf2f(raw.y >> 16);
    }
    __syncthreads();

    const int j = tid >> 3;
    const int k0 = (tid & 7) * 4;

    float o0 = 0.f, o1 = 0.f, o2 = 0.f, o3 = 0.f;
#pragma unroll
    for (int h = 0; h < NCB; ++h) {
        float a = ylds[h * 64 + j];
        float4 bb = *(const float4*)&ylds[h * 64 + 32 + k0];
        o0 += a * bb.x; o1 += a * bb.y; o2 += a * bb.z; o3 += a * bb.w;
    }
    o0 *= 0.25f; o1 *= 0.25f; o2 *= 0.25f; o3 *= 0.25f;

    float ss = o0 * o0 + o1 * o1 + o2 * o2 + o3 * o3;
#pragma unroll
    for (int off = 32; off >= 1; off >>= 1)
        ss += __shfl_xor(ss, off, 64);

    const int lane = tid & 63, w = tid >> 6;
    if (lane == 0) red[w] = ss;
    __syncthreads();
    float tot = red[0] + red[1] + red[2] + red[3];
    float scale = rsqrtf(tot * (1.0f / 1024.0f) + 1e-12f);

    float4 o;
    o.x = o0 * scale; o.y = o1 * scale; o.z = o2 * scale; o.w = o3 * scale;
    *(float4*)(out + (size_t)t * 1024 + tid * 4) = o;
}

extern "C" void kernel_launch(void* const* d_in, const int* in_sizes, int n_in,
                              void* d_out, int out_size, void* d_ws, size_t ws_size,
                              hipStream_t stream) {
    const float* x   = (const float*)d_in[0];
    const float* wgt = (const float*)d_in[1];
    float* out = (float*)d_out;

    unsigned short* Bt = (unsigned short*)d_ws;                       //  2 MB
    unsigned short* Y  = (unsigned short*)((char*)d_ws + (2u << 20)); // 16 MB

    conv_w_kernel<<<NOUT * KDIM / 8 / 256, 256, 0, stream>>>(wgt, Bt);
    gemm_fused_kernel<<<(NOUT / 128) * (NTOK / 128), 256, 0, stream>>>(x, Bt, Y);
    epilogue_kernel<<<NTOK, 256, 0, stream>>>(Y, out);
}